// Round 5
// baseline (339.967 us; speedup 1.0000x reference)
//
#include <hip/hip_runtime.h>

// TransformerConv x2 on MI355X — MFMA GEMM (fused 4-out) + bf16 gather attention
// with qWe/sae scalar factorization and exp2-domain online softmax.
// N=50000, E=800000, H=4, C=32, D=128.

#define TPB 256

typedef __attribute__((ext_vector_type(8))) short short8v;
typedef __attribute__((ext_vector_type(4))) float f32x4;

__device__ __forceinline__ unsigned short f2bf(float f) {
    unsigned u = __float_as_uint(f);
    u = (u + 0x7FFFu + ((u >> 16) & 1u)) >> 16;
    return (unsigned short)u;
}
__device__ __forceinline__ float bf2f(unsigned short s) {
    return __uint_as_float((unsigned)s << 16);
}
__device__ __forceinline__ float4 bf4_to_f4(ushort4 u) {
    return make_float4(bf2f(u.x), bf2f(u.y), bf2f(u.z), bf2f(u.w));
}
__device__ __forceinline__ float exp2_hw(float x) {
    float r;
    asm("v_exp_f32 %0, %1" : "=v"(r) : "v"(x));
    return r;
}

// ---- fp32 -> bf16 convert (vectorized) ----
__global__ void __launch_bounds__(TPB) cvt_bf16_k(const float* __restrict__ in,
                                                  unsigned short* __restrict__ out,
                                                  int n4)
{
    int i = blockIdx.x * TPB + threadIdx.x;
    if (i >= n4) return;
    float4 v = *(const float4*)(in + (size_t)i * 4);
    ushort4 o;
    o.x = f2bf(v.x); o.y = f2bf(v.y); o.z = f2bf(v.z); o.w = f2bf(v.w);
    *(ushort4*)(out + (size_t)i * 4) = o;
}

// ---- pack 8 weight matrices (both layers) into MFMA B-fragment layout ----
__global__ void __launch_bounds__(TPB) prepack_k(
    const float* __restrict__ Wq1, const float* __restrict__ Wk1,
    const float* __restrict__ Wv1, const float* __restrict__ Ws1,
    const float* __restrict__ Wq2, const float* __restrict__ Wk2,
    const float* __restrict__ Wv2, const float* __restrict__ Ws2,
    unsigned short* __restrict__ pack)
{
    int i = blockIdx.x * TPB + threadIdx.x;   // 131072 total
    int j = i & 7, l = (i >> 3) & 63, t = (i >> 9) & 3, c = (i >> 11) & 7, g = (i >> 14) & 7;
    const float* Wt[8] = {Wq1, Wk1, Wv1, Ws1, Wq2, Wk2, Wv2, Ws2};
    const float* W = Wt[g];
    int kk = t * 32 + (l >> 4) * 8 + j;
    int nn = c * 16 + (l & 15);
    pack[i] = f2bf(W[kk * 128 + nn]);
}

// ---- fused MFMA GEMM: q/k/v (bf16 out) + skip (fp32 out), A resident ----
// Block: 256 threads = 4 waves; wave computes 32 rows x 128 cols; K=128 in regs.
__global__ void __launch_bounds__(TPB) gemm_mfma_k(
    const unsigned short* __restrict__ A, int M,
    const unsigned short* __restrict__ pack,   // 4 groups x 16384
    const float* __restrict__ bq, const float* __restrict__ bk,
    const float* __restrict__ bv, const float* __restrict__ bs,
    unsigned short* __restrict__ oq, unsigned short* __restrict__ ok,
    unsigned short* __restrict__ ov, float* __restrict__ os)
{
    const int row0 = blockIdx.x * 128;
    const int wv = threadIdx.x >> 6;
    const int lane = threadIdx.x & 63;
    const int rbase = row0 + wv * 32;
    const int rlo = lane & 15;
    const int kg = (lane >> 4) * 8;
    const int rof = (lane >> 4) * 4;

    const short8v z8 = {0, 0, 0, 0, 0, 0, 0, 0};
    short8v a[2][4];
#pragma unroll
    for (int m = 0; m < 2; ++m) {
        int row = rbase + m * 16 + rlo;
#pragma unroll
        for (int t = 0; t < 4; ++t)
            a[m][t] = (row < M) ? *(const short8v*)(A + (size_t)row * 128 + t * 32 + kg)
                                : z8;
    }

    for (int g = 0; g < 4; ++g) {
        f32x4 acc[2][8];
#pragma unroll
        for (int m = 0; m < 2; ++m)
#pragma unroll
            for (int c = 0; c < 8; ++c)
                acc[m][c] = (f32x4){0.f, 0.f, 0.f, 0.f};

        const unsigned short* bp = pack + (size_t)g * (8 * 4 * 512);
#pragma unroll
        for (int c = 0; c < 8; ++c) {
            short8v b[4];
#pragma unroll
            for (int t = 0; t < 4; ++t)
                b[t] = *(const short8v*)(bp + (c * 4 + t) * 512 + lane * 8);
#pragma unroll
            for (int t = 0; t < 4; ++t) {
                acc[0][c] = __builtin_amdgcn_mfma_f32_16x16x32_bf16(a[0][t], b[t], acc[0][c], 0, 0, 0);
                acc[1][c] = __builtin_amdgcn_mfma_f32_16x16x32_bf16(a[1][t], b[t], acc[1][c], 0, 0, 0);
            }
        }

        const float* bias = g == 0 ? bq : (g == 1 ? bk : (g == 2 ? bv : bs));
        if (g == 3) {
#pragma unroll
            for (int c = 0; c < 8; ++c) {
                float bb = bias[c * 16 + rlo];
#pragma unroll
                for (int m = 0; m < 2; ++m)
#pragma unroll
                    for (int j = 0; j < 4; ++j) {
                        int row = rbase + m * 16 + rof + j;
                        if (row < M) os[(size_t)row * 128 + c * 16 + rlo] = acc[m][c][j] + bb;
                    }
            }
        } else {
            unsigned short* out = g == 0 ? oq : (g == 1 ? ok : ov);
#pragma unroll
            for (int c = 0; c < 8; ++c) {
                float bb = bias[c * 16 + rlo];
#pragma unroll
                for (int m = 0; m < 2; ++m)
#pragma unroll
                    for (int j = 0; j < 4; ++j) {
                        int row = rbase + m * 16 + rof + j;
                        if (row < M) out[(size_t)row * 128 + c * 16 + rlo] = f2bf(acc[m][c][j] + bb);
                    }
            }
        }
    }
}

// ---------------- CSR build ----------------
__global__ void __launch_bounds__(TPB) hist_k(const int* __restrict__ dst,
                                              int* __restrict__ deg, int E)
{
    int e = blockIdx.x * TPB + threadIdx.x;
    if (e < E) atomicAdd(&deg[dst[e]], 1);
}

__global__ void __launch_bounds__(TPB) scan_a_k(const int* __restrict__ deg, int n,
                                                int* __restrict__ incl,
                                                int* __restrict__ bsum)
{
    __shared__ int ts[TPB];
    const int base = blockIdx.x * 1024;
    int vals[4], s = 0;
#pragma unroll
    for (int j = 0; j < 4; ++j) {
        int i = base + threadIdx.x * 4 + j;
        vals[j] = (i < n) ? deg[i] : 0;
        s += vals[j];
    }
    ts[threadIdx.x] = s;
    __syncthreads();
    for (int off = 1; off < TPB; off <<= 1) {
        int u = (threadIdx.x >= off) ? ts[threadIdx.x - off] : 0;
        __syncthreads();
        ts[threadIdx.x] += u;
        __syncthreads();
    }
    int run = ts[threadIdx.x] - s;
#pragma unroll
    for (int j = 0; j < 4; ++j) {
        run += vals[j];
        int i = base + threadIdx.x * 4 + j;
        if (i < n) incl[i] = run;
    }
    if (threadIdx.x == TPB - 1) bsum[blockIdx.x] = ts[TPB - 1];
}

__global__ void __launch_bounds__(TPB) scan_b_k(int* __restrict__ bsum, int nb)
{
    __shared__ int ts[TPB];
    int t = threadIdx.x;
    int v = (t < nb) ? bsum[t] : 0;
    ts[t] = v;
    __syncthreads();
    for (int off = 1; off < TPB; off <<= 1) {
        int u = (t >= off) ? ts[t - off] : 0;
        __syncthreads();
        ts[t] += u;
        __syncthreads();
    }
    if (t < nb) bsum[t] = ts[t] - v;
}

__global__ void __launch_bounds__(TPB) finalize_k(const int* __restrict__ incl,
                                                  const int* __restrict__ deg,
                                                  const int* __restrict__ bsum, int n,
                                                  int* __restrict__ row_ptr,
                                                  int* __restrict__ cursor)
{
    const int base = blockIdx.x * 1024;
    const int boff = bsum[blockIdx.x];
#pragma unroll
    for (int j = 0; j < 4; ++j) {
        int i = base + threadIdx.x * 4 + j;
        if (i < n) {
            int iv = incl[i] + boff;
            int st = iv - deg[i];
            row_ptr[i] = st;
            cursor[i] = st;
            if (i == n - 1) row_ptr[n] = iv;
        }
    }
}

__global__ void __launch_bounds__(TPB) scatter_k(
    const int* __restrict__ src, const int* __restrict__ dst,
    const float* __restrict__ ea, int* __restrict__ cursor,
    int* __restrict__ csr_src, float* __restrict__ csr_ea, int E)
{
    int e = blockIdx.x * TPB + threadIdx.x;
    if (e >= E) return;
    int pos = atomicAdd(&cursor[dst[e]], 1);
    csr_src[pos] = src[e];
    csr_ea[pos] = ea[e];
}

// ---- fused per-node gather attention (bf16 q/k/v, qWe/sae factorization) ----
// Wave per node. Lanes 0..31 own k-comps 4*lane..+3; lanes 32..63 own v-comps.
// alpha = (q~.k) + ea*qwe  where q~ = q * (1/sqrt(32) * log2(e)), exp2 domain.
template <bool BF16OUT>
__global__ void __launch_bounds__(TPB) node_attn_k(
    const unsigned short* __restrict__ q, const unsigned short* __restrict__ k,
    const unsigned short* __restrict__ v, const float* __restrict__ skip,
    const float* __restrict__ We,
    const int* __restrict__ row_ptr, const int* __restrict__ csr_src,
    const float* __restrict__ csr_ea,
    void* __restrict__ outp, int n)
{
    const int node = blockIdx.x * 4 + (threadIdx.x >> 6);
    if (node >= n) return;
    const int lane = threadIdx.x & 63;
    const bool vside = lane >= 32;
    const int c4 = (lane & 31) * 4;
    const unsigned short* gbase = vside ? v : k;

    const float C2 = 0.17677669529663687f * 1.44269504088896f; // 1/sqrt(32)*log2e
    const float4 we4 = *(const float4*)(We + c4);
    float4 qv = bf4_to_f4(*(const ushort4*)(q + (size_t)node * 128 + c4));
    qv.x *= C2; qv.y *= C2; qv.z *= C2; qv.w *= C2;

    // per-head scalar qwe = (q . We) * C2 (valid on every lane of the 8-group)
    float qwe = qv.x * we4.x + qv.y * we4.y + qv.z * we4.z + qv.w * we4.w;
    qwe += __shfl_xor(qwe, 1);
    qwe += __shfl_xor(qwe, 2);
    qwe += __shfl_xor(qwe, 4);

    const int p0 = row_ptr[node], p1 = row_ptr[node + 1];

    float m = -3.4e38f, l = 0.f, sae = 0.f;
    float4 acc = make_float4(0.f, 0.f, 0.f, 0.f);

    for (int base = p0; base < p1; base += 64) {
        const int cnt = min(64, p1 - base);
        int sv = 0;
        float av = 0.f;
        if (lane < cnt) {
            sv = csr_src[base + lane];
            av = csr_ea[base + lane];
        }
        int j = 0;
        for (; j + 4 <= cnt; j += 4) {
            int s0 = __shfl(sv, j), s1 = __shfl(sv, j + 1);
            int s2 = __shfl(sv, j + 2), s3 = __shfl(sv, j + 3);
            float a0 = __shfl(av, j), a1 = __shfl(av, j + 1);
            float a2 = __shfl(av, j + 2), a3 = __shfl(av, j + 3);
            ushort4 u0 = *(const ushort4*)(gbase + (unsigned)s0 * 128u + c4);
            ushort4 u1 = *(const ushort4*)(gbase + (unsigned)s1 * 128u + c4);
            ushort4 u2 = *(const ushort4*)(gbase + (unsigned)s2 * 128u + c4);
            ushort4 u3 = *(const ushort4*)(gbase + (unsigned)s3 * 128u + c4);
            float4 f0 = bf4_to_f4(u0), f1 = bf4_to_f4(u1);
            float4 f2 = bf4_to_f4(u2), f3 = bf4_to_f4(u3);
            float d0 = f0.x * qv.x + f0.y * qv.y + f0.z * qv.z + f0.w * qv.w;
            float d1 = f1.x * qv.x + f1.y * qv.y + f1.z * qv.z + f1.w * qv.w;
            float d2 = f2.x * qv.x + f2.y * qv.y + f2.z * qv.z + f2.w * qv.w;
            float d3 = f3.x * qv.x + f3.y * qv.y + f3.z * qv.z + f3.w * qv.w;
            d0 += __shfl_xor(d0, 1); d0 += __shfl_xor(d0, 2); d0 += __shfl_xor(d0, 4);
            d1 += __shfl_xor(d1, 1); d1 += __shfl_xor(d1, 2); d1 += __shfl_xor(d1, 4);
            d2 += __shfl_xor(d2, 1); d2 += __shfl_xor(d2, 2); d2 += __shfl_xor(d2, 4);
            d3 += __shfl_xor(d3, 1); d3 += __shfl_xor(d3, 2); d3 += __shfl_xor(d3, 4);
            float al0 = fmaf(a0, qwe, __shfl(d0, lane & 31));
            float al1 = fmaf(a1, qwe, __shfl(d1, lane & 31));
            float al2 = fmaf(a2, qwe, __shfl(d2, lane & 31));
            float al3 = fmaf(a3, qwe, __shfl(d3, lane & 31));
            float mn = fmaxf(m, fmaxf(fmaxf(al0, al1), fmaxf(al2, al3)));
            float sc = exp2_hw(m - mn);
            float pe0 = exp2_hw(al0 - mn), pe1 = exp2_hw(al1 - mn);
            float pe2 = exp2_hw(al2 - mn), pe3 = exp2_hw(al3 - mn);
            l = fmaf(l, sc, (pe0 + pe1) + (pe2 + pe3));
            sae = fmaf(sae, sc, fmaf(pe3, a3, fmaf(pe2, a2, fmaf(pe1, a1, pe0 * a0))));
            acc.x = fmaf(acc.x, sc, fmaf(pe0, f0.x, fmaf(pe1, f1.x, fmaf(pe2, f2.x, pe3 * f3.x))));
            acc.y = fmaf(acc.y, sc, fmaf(pe0, f0.y, fmaf(pe1, f1.y, fmaf(pe2, f2.y, pe3 * f3.y))));
            acc.z = fmaf(acc.z, sc, fmaf(pe0, f0.z, fmaf(pe1, f1.z, fmaf(pe2, f2.z, pe3 * f3.z))));
            acc.w = fmaf(acc.w, sc, fmaf(pe0, f0.w, fmaf(pe1, f1.w, fmaf(pe2, f2.w, pe3 * f3.w))));
            m = mn;
        }
        for (; j < cnt; ++j) {
            int s0 = __shfl(sv, j);
            float a0 = __shfl(av, j);
            ushort4 u0 = *(const ushort4*)(gbase + (unsigned)s0 * 128u + c4);
            float4 f0 = bf4_to_f4(u0);
            float d0 = f0.x * qv.x + f0.y * qv.y + f0.z * qv.z + f0.w * qv.w;
            d0 += __shfl_xor(d0, 1); d0 += __shfl_xor(d0, 2); d0 += __shfl_xor(d0, 4);
            float al0 = fmaf(a0, qwe, __shfl(d0, lane & 31));
            float mn = fmaxf(m, al0);
            float sc = exp2_hw(m - mn);
            float pe0 = exp2_hw(al0 - mn);
            l = fmaf(l, sc, pe0);
            sae = fmaf(sae, sc, pe0 * a0);
            acc.x = fmaf(acc.x, sc, pe0 * f0.x);
            acc.y = fmaf(acc.y, sc, pe0 * f0.y);
            acc.z = fmaf(acc.z, sc, pe0 * f0.z);
            acc.w = fmaf(acc.w, sc, pe0 * f0.w);
            m = mn;
        }
    }

    if (vside) {
        float inv = 1.f / (l + 1e-16f);
        float4 sk = *(const float4*)(skip + (size_t)node * 128 + c4);
        float o0 = fmaxf(fmaf(fmaf(sae, we4.x, acc.x), inv, sk.x), 0.f);
        float o1 = fmaxf(fmaf(fmaf(sae, we4.y, acc.y), inv, sk.y), 0.f);
        float o2 = fmaxf(fmaf(fmaf(sae, we4.z, acc.z), inv, sk.z), 0.f);
        float o3 = fmaxf(fmaf(fmaf(sae, we4.w, acc.w), inv, sk.w), 0.f);
        if (BF16OUT) {
            ushort4 o;
            o.x = f2bf(o0); o.y = f2bf(o1); o.z = f2bf(o2); o.w = f2bf(o3);
            *(ushort4*)((unsigned short*)outp + (size_t)node * 128 + c4) = o;
        } else {
            *(float4*)((float*)outp + (size_t)node * 128 + c4) =
                make_float4(o0, o1, o2, o3);
        }
    }
}

extern "C" void kernel_launch(void* const* d_in, const int* in_sizes, int n_in,
                              void* d_out, int out_size, void* d_ws, size_t ws_size,
                              hipStream_t stream)
{
    const float* x   = (const float*)d_in[0];
    const int*   ei  = (const int*)d_in[1];
    const float* ea  = (const float*)d_in[2];
    const float* Wq1 = (const float*)d_in[3];  const float* bq1 = (const float*)d_in[4];
    const float* Wk1 = (const float*)d_in[5];  const float* bk1 = (const float*)d_in[6];
    const float* Wv1 = (const float*)d_in[7];  const float* bv1 = (const float*)d_in[8];
    const float* We1 = (const float*)d_in[9];
    const float* Ws1 = (const float*)d_in[10]; const float* bs1 = (const float*)d_in[11];
    const float* Wq2 = (const float*)d_in[12]; const float* bq2 = (const float*)d_in[13];
    const float* Wk2 = (const float*)d_in[14]; const float* bk2 = (const float*)d_in[15];
    const float* Wv2 = (const float*)d_in[16]; const float* bv2 = (const float*)d_in[17];
    const float* We2 = (const float*)d_in[18];
    const float* Ws2 = (const float*)d_in[19]; const float* bs2 = (const float*)d_in[20];

    const int N = in_sizes[0] / 128;
    const int E = in_sizes[1] / 2;
    const int* src = ei;
    const int* dst = ei + E;
    float* outf = (float*)d_out;

    // workspace layout
    unsigned short* q  = (unsigned short*)d_ws;          // N*128 bf16
    unsigned short* k  = q + (size_t)N * 128;
    unsigned short* v  = k + (size_t)N * 128;
    float*          s  = (float*)(v + (size_t)N * 128);  // N*128 f32 skip
    unsigned short* xb = (unsigned short*)(s + (size_t)N * 128); // bf16 x / h
    unsigned short* pk = xb + (size_t)N * 128;           // 131072 (both layers)
    int*   row_ptr = (int*)(pk + 131072);                // N+1
    int*   deg     = row_ptr + (N + 1);
    int*   incl    = deg + N;
    int*   cursor  = incl + N;
    int*   bsum    = cursor + N;                         // 256
    int*   csr_src = bsum + 256;                         // E
    float* csr_ea  = (float*)(csr_src + E);              // E

    const int gE   = (E + TPB - 1) / TPB;
    const int nb   = (N + 1023) / 1024;
    const int gN4  = (N + 3) / 4;
    const int gCv  = (N * 128 / 4 + TPB - 1) / TPB;
    const int gG   = (N + 127) / 128;

    // ---- CSR build (shared by both layers) ----
    hipMemsetAsync(deg, 0, (size_t)N * sizeof(int), stream);
    hist_k<<<gE, TPB, 0, stream>>>(dst, deg, E);
    scan_a_k<<<nb, TPB, 0, stream>>>(deg, N, incl, bsum);
    scan_b_k<<<1, TPB, 0, stream>>>(bsum, nb);
    finalize_k<<<nb, TPB, 0, stream>>>(incl, deg, bsum, N, row_ptr, cursor);
    scatter_k<<<gE, TPB, 0, stream>>>(src, dst, ea, cursor, csr_src, csr_ea, E);

    // ---- packs + input convert ----
    prepack_k<<<131072 / TPB, TPB, 0, stream>>>(Wq1, Wk1, Wv1, Ws1,
                                                Wq2, Wk2, Wv2, Ws2, pk);
    cvt_bf16_k<<<gCv, TPB, 0, stream>>>(x, xb, N * 128 / 4);

    // ---- layer 1 ----
    gemm_mfma_k<<<gG, TPB, 0, stream>>>(xb, N, pk, bq1, bk1, bv1, bs1, q, k, v, s);
    node_attn_k<true><<<gN4, TPB, 0, stream>>>(q, k, v, s, We1, row_ptr, csr_src,
                                               csr_ea, xb, N);  // h -> bf16 (reuse xb)
    // ---- layer 2 ----
    gemm_mfma_k<<<gG, TPB, 0, stream>>>(xb, N, pk + 65536, bq2, bk2, bv2, bs2,
                                        q, k, v, s);
    node_attn_k<false><<<gN4, TPB, 0, stream>>>(q, k, v, s, We2, row_ptr, csr_src,
                                                csr_ea, outf, N);
}

// Round 6
// 315.926 us; speedup vs baseline: 1.0761x; 1.0761x over previous
//
#include <hip/hip_runtime.h>

// TransformerConv x2 on MI355X — MFMA GEMM + 32-lane-per-node gather attention.
// N=50000, E=800000, H=4, C=32, D=128.

#define TPB 256

typedef __attribute__((ext_vector_type(8))) short short8v;
typedef __attribute__((ext_vector_type(4))) float f32x4;

__device__ __forceinline__ unsigned short f2bf(float f) {
    unsigned u = __float_as_uint(f);
    u = (u + 0x7FFFu + ((u >> 16) & 1u)) >> 16;
    return (unsigned short)u;
}
__device__ __forceinline__ float bf2f(unsigned short s) {
    return __uint_as_float((unsigned)s << 16);
}
__device__ __forceinline__ float4 bf4_to_f4(ushort4 u) {
    return make_float4(bf2f(u.x), bf2f(u.y), bf2f(u.z), bf2f(u.w));
}
__device__ __forceinline__ float exp2_hw(float x) {
    float r;
    asm("v_exp_f32 %0, %1" : "=v"(r) : "v"(x));
    return r;
}

// ---- pack 8 weight matrices (both layers) into MFMA B-fragment layout ----
__global__ void __launch_bounds__(TPB) prepack_k(
    const float* __restrict__ Wq1, const float* __restrict__ Wk1,
    const float* __restrict__ Wv1, const float* __restrict__ Ws1,
    const float* __restrict__ Wq2, const float* __restrict__ Wk2,
    const float* __restrict__ Wv2, const float* __restrict__ Ws2,
    unsigned short* __restrict__ pack)
{
    int i = blockIdx.x * TPB + threadIdx.x;   // 131072 total
    int j = i & 7, l = (i >> 3) & 63, t = (i >> 9) & 3, c = (i >> 11) & 7, g = (i >> 14) & 7;
    const float* Wt[8] = {Wq1, Wk1, Wv1, Ws1, Wq2, Wk2, Wv2, Ws2};
    const float* W = Wt[g];
    int kk = t * 32 + (l >> 4) * 8 + j;
    int nn = c * 16 + (l & 15);
    pack[i] = f2bf(W[kk * 128 + nn]);
}

// ---- MFMA GEMM: g = blockIdx.y in {q,k,v} -> bf16 out, g==3 (skip) -> fp32 ----
// A is fp32 (layer 1, converted inline) or bf16 (layer 2).
template <bool AF32>
__global__ void __launch_bounds__(TPB) gemm_mfma_k(
    const void* __restrict__ Av, int M,
    const unsigned short* __restrict__ pack,
    const float* __restrict__ bq, const float* __restrict__ bk,
    const float* __restrict__ bv, const float* __restrict__ bs,
    unsigned short* __restrict__ oq, unsigned short* __restrict__ ok,
    unsigned short* __restrict__ ov, float* __restrict__ os)
{
    const int g = blockIdx.y;
    const int row0 = blockIdx.x * 128;
    const int wv = threadIdx.x >> 6;
    const int lane = threadIdx.x & 63;
    const int rbase = row0 + wv * 32;
    const int rlo = lane & 15;
    const int kg = (lane >> 4) * 8;
    const int rof = (lane >> 4) * 4;

    const short8v z8 = {0, 0, 0, 0, 0, 0, 0, 0};
    short8v a[2][4];
#pragma unroll
    for (int m = 0; m < 2; ++m) {
        int row = rbase + m * 16 + rlo;
        if (row >= M) {
#pragma unroll
            for (int t = 0; t < 4; ++t) a[m][t] = z8;
        } else if (AF32) {
            const float* Af = (const float*)Av + (size_t)row * 128 + kg;
#pragma unroll
            for (int t = 0; t < 4; ++t) {
                float4 lo = *(const float4*)(Af + t * 32);
                float4 hi = *(const float4*)(Af + t * 32 + 4);
                short8v p;
                p[0] = (short)f2bf(lo.x); p[1] = (short)f2bf(lo.y);
                p[2] = (short)f2bf(lo.z); p[3] = (short)f2bf(lo.w);
                p[4] = (short)f2bf(hi.x); p[5] = (short)f2bf(hi.y);
                p[6] = (short)f2bf(hi.z); p[7] = (short)f2bf(hi.w);
                a[m][t] = p;
            }
        } else {
            const unsigned short* Ab = (const unsigned short*)Av + (size_t)row * 128 + kg;
#pragma unroll
            for (int t = 0; t < 4; ++t)
                a[m][t] = *(const short8v*)(Ab + t * 32);
        }
    }

    f32x4 acc[2][8];
#pragma unroll
    for (int m = 0; m < 2; ++m)
#pragma unroll
        for (int c = 0; c < 8; ++c)
            acc[m][c] = (f32x4){0.f, 0.f, 0.f, 0.f};

    const unsigned short* bp = pack + (size_t)g * (8 * 4 * 512);
#pragma unroll
    for (int c = 0; c < 8; ++c) {
        short8v b[4];
#pragma unroll
        for (int t = 0; t < 4; ++t)
            b[t] = *(const short8v*)(bp + (c * 4 + t) * 512 + lane * 8);
#pragma unroll
        for (int t = 0; t < 4; ++t) {
            acc[0][c] = __builtin_amdgcn_mfma_f32_16x16x32_bf16(a[0][t], b[t], acc[0][c], 0, 0, 0);
            acc[1][c] = __builtin_amdgcn_mfma_f32_16x16x32_bf16(a[1][t], b[t], acc[1][c], 0, 0, 0);
        }
    }

    const float* bias = g == 0 ? bq : (g == 1 ? bk : (g == 2 ? bv : bs));
    if (g == 3) {
#pragma unroll
        for (int c = 0; c < 8; ++c) {
            float bb = bias[c * 16 + rlo];
#pragma unroll
            for (int m = 0; m < 2; ++m)
#pragma unroll
                for (int j = 0; j < 4; ++j) {
                    int row = rbase + m * 16 + rof + j;
                    if (row < M) os[(size_t)row * 128 + c * 16 + rlo] = acc[m][c][j] + bb;
                }
        }
    } else {
        unsigned short* out = g == 0 ? oq : (g == 1 ? ok : ov);
#pragma unroll
        for (int c = 0; c < 8; ++c) {
            float bb = bias[c * 16 + rlo];
#pragma unroll
            for (int m = 0; m < 2; ++m)
#pragma unroll
                for (int j = 0; j < 4; ++j) {
                    int row = rbase + m * 16 + rof + j;
                    if (row < M) out[(size_t)row * 128 + c * 16 + rlo] = f2bf(acc[m][c][j] + bb);
                }
        }
    }
}

// ---------------- CSR build ----------------
__global__ void __launch_bounds__(TPB) hist_k(const int* __restrict__ dst,
                                              int* __restrict__ deg, int E)
{
    int e = blockIdx.x * TPB + threadIdx.x;
    if (e < E) atomicAdd(&deg[dst[e]], 1);
}

__global__ void __launch_bounds__(TPB) scan_a_k(const int* __restrict__ deg, int n,
                                                int* __restrict__ incl,
                                                int* __restrict__ bsum)
{
    __shared__ int ts[TPB];
    const int base = blockIdx.x * 1024;
    int vals[4], s = 0;
#pragma unroll
    for (int j = 0; j < 4; ++j) {
        int i = base + threadIdx.x * 4 + j;
        vals[j] = (i < n) ? deg[i] : 0;
        s += vals[j];
    }
    ts[threadIdx.x] = s;
    __syncthreads();
    for (int off = 1; off < TPB; off <<= 1) {
        int u = (threadIdx.x >= off) ? ts[threadIdx.x - off] : 0;
        __syncthreads();
        ts[threadIdx.x] += u;
        __syncthreads();
    }
    int run = ts[threadIdx.x] - s;
#pragma unroll
    for (int j = 0; j < 4; ++j) {
        run += vals[j];
        int i = base + threadIdx.x * 4 + j;
        if (i < n) incl[i] = run;
    }
    if (threadIdx.x == TPB - 1) bsum[blockIdx.x] = ts[TPB - 1];
}

__global__ void __launch_bounds__(TPB) scan_b_k(int* __restrict__ bsum, int nb)
{
    __shared__ int ts[TPB];
    int t = threadIdx.x;
    int v = (t < nb) ? bsum[t] : 0;
    ts[t] = v;
    __syncthreads();
    for (int off = 1; off < TPB; off <<= 1) {
        int u = (t >= off) ? ts[t - off] : 0;
        __syncthreads();
        ts[t] += u;
        __syncthreads();
    }
    if (t < nb) bsum[t] = ts[t] - v;
}

__global__ void __launch_bounds__(TPB) finalize_k(const int* __restrict__ incl,
                                                  const int* __restrict__ deg,
                                                  const int* __restrict__ bsum, int n,
                                                  int* __restrict__ row_ptr,
                                                  int* __restrict__ cursor)
{
    const int base = blockIdx.x * 1024;
    const int boff = bsum[blockIdx.x];
#pragma unroll
    for (int j = 0; j < 4; ++j) {
        int i = base + threadIdx.x * 4 + j;
        if (i < n) {
            int iv = incl[i] + boff;
            int st = iv - deg[i];
            row_ptr[i] = st;
            cursor[i] = st;
            if (i == n - 1) row_ptr[n] = iv;
        }
    }
}

__global__ void __launch_bounds__(TPB) scatter_k(
    const int* __restrict__ src, const int* __restrict__ dst,
    const float* __restrict__ ea, int* __restrict__ cursor,
    int2* __restrict__ csr_pair, int E)
{
    int e = blockIdx.x * TPB + threadIdx.x;
    if (e >= E) return;
    int pos = atomicAdd(&cursor[dst[e]], 1);
    csr_pair[pos] = make_int2(src[e], __float_as_int(ea[e]));
}

// ---- fused per-node gather attention: 32 lanes per node, 2 nodes per wave ----
// Lane owns comps 4*l32..+3; head = l32>>3 (8 lanes/head). Dot reduce = 3 xor
// shfl within 8-lane groups; alpha lands on the lanes that consume it.
// alpha = (q~ . k) + ea*qwe in exp2 domain; Sigma pe*ea folds We in epilogue.
template <bool BF16OUT>
__global__ void __launch_bounds__(TPB) node_attn_k(
    const unsigned short* __restrict__ q, const unsigned short* __restrict__ k,
    const unsigned short* __restrict__ v, const float* __restrict__ skip,
    const float* __restrict__ We,
    const int* __restrict__ row_ptr, const int2* __restrict__ csr_pair,
    void* __restrict__ outp, int n)
{
    const int node = blockIdx.x * 8 + (threadIdx.x >> 5);
    if (node >= n) return;
    const int l32 = threadIdx.x & 31;
    const int c4 = l32 * 4;

    const float C2 = 0.17677669529663687f * 1.44269504088896f; // 1/sqrt(32)*log2e
    const float4 we4 = *(const float4*)(We + c4);
    float4 qv = bf4_to_f4(*(const ushort4*)(q + (size_t)node * 128 + c4));
    qv.x *= C2; qv.y *= C2; qv.z *= C2; qv.w *= C2;

    float qwe = qv.x * we4.x + qv.y * we4.y + qv.z * we4.z + qv.w * we4.w;
    qwe += __shfl_xor(qwe, 1);
    qwe += __shfl_xor(qwe, 2);
    qwe += __shfl_xor(qwe, 4);

    const int p0 = row_ptr[node], p1 = row_ptr[node + 1];

    float m = -3.4e38f, l = 0.f, sae = 0.f;
    float4 acc = make_float4(0.f, 0.f, 0.f, 0.f);

    int j = p0;
    for (; j + 4 <= p1; j += 4) {
        int2 pr0 = csr_pair[j],     pr1 = csr_pair[j + 1];
        int2 pr2 = csr_pair[j + 2], pr3 = csr_pair[j + 3];
        ushort4 ku0 = *(const ushort4*)(k + (unsigned)pr0.x * 128u + c4);
        ushort4 ku1 = *(const ushort4*)(k + (unsigned)pr1.x * 128u + c4);
        ushort4 ku2 = *(const ushort4*)(k + (unsigned)pr2.x * 128u + c4);
        ushort4 ku3 = *(const ushort4*)(k + (unsigned)pr3.x * 128u + c4);
        ushort4 vu0 = *(const ushort4*)(v + (unsigned)pr0.x * 128u + c4);
        ushort4 vu1 = *(const ushort4*)(v + (unsigned)pr1.x * 128u + c4);
        ushort4 vu2 = *(const ushort4*)(v + (unsigned)pr2.x * 128u + c4);
        ushort4 vu3 = *(const ushort4*)(v + (unsigned)pr3.x * 128u + c4);
        float4 kf0 = bf4_to_f4(ku0), kf1 = bf4_to_f4(ku1);
        float4 kf2 = bf4_to_f4(ku2), kf3 = bf4_to_f4(ku3);
        float d0 = kf0.x * qv.x + kf0.y * qv.y + kf0.z * qv.z + kf0.w * qv.w;
        float d1 = kf1.x * qv.x + kf1.y * qv.y + kf1.z * qv.z + kf1.w * qv.w;
        float d2 = kf2.x * qv.x + kf2.y * qv.y + kf2.z * qv.z + kf2.w * qv.w;
        float d3 = kf3.x * qv.x + kf3.y * qv.y + kf3.z * qv.z + kf3.w * qv.w;
        d0 += __shfl_xor(d0, 1); d0 += __shfl_xor(d0, 2); d0 += __shfl_xor(d0, 4);
        d1 += __shfl_xor(d1, 1); d1 += __shfl_xor(d1, 2); d1 += __shfl_xor(d1, 4);
        d2 += __shfl_xor(d2, 1); d2 += __shfl_xor(d2, 2); d2 += __shfl_xor(d2, 4);
        d3 += __shfl_xor(d3, 1); d3 += __shfl_xor(d3, 2); d3 += __shfl_xor(d3, 4);
        float al0 = fmaf(__int_as_float(pr0.y), qwe, d0);
        float al1 = fmaf(__int_as_float(pr1.y), qwe, d1);
        float al2 = fmaf(__int_as_float(pr2.y), qwe, d2);
        float al3 = fmaf(__int_as_float(pr3.y), qwe, d3);
        float mn = fmaxf(m, fmaxf(fmaxf(al0, al1), fmaxf(al2, al3)));
        float sc = exp2_hw(m - mn);
        float pe0 = exp2_hw(al0 - mn), pe1 = exp2_hw(al1 - mn);
        float pe2 = exp2_hw(al2 - mn), pe3 = exp2_hw(al3 - mn);
        float4 vf0 = bf4_to_f4(vu0), vf1 = bf4_to_f4(vu1);
        float4 vf2 = bf4_to_f4(vu2), vf3 = bf4_to_f4(vu3);
        l = fmaf(l, sc, (pe0 + pe1) + (pe2 + pe3));
        sae = fmaf(sae, sc, fmaf(pe3, __int_as_float(pr3.y),
                   fmaf(pe2, __int_as_float(pr2.y),
                   fmaf(pe1, __int_as_float(pr1.y), pe0 * __int_as_float(pr0.y)))));
        acc.x = fmaf(acc.x, sc, fmaf(pe0, vf0.x, fmaf(pe1, vf1.x, fmaf(pe2, vf2.x, pe3 * vf3.x))));
        acc.y = fmaf(acc.y, sc, fmaf(pe0, vf0.y, fmaf(pe1, vf1.y, fmaf(pe2, vf2.y, pe3 * vf3.y))));
        acc.z = fmaf(acc.z, sc, fmaf(pe0, vf0.z, fmaf(pe1, vf1.z, fmaf(pe2, vf2.z, pe3 * vf3.z))));
        acc.w = fmaf(acc.w, sc, fmaf(pe0, vf0.w, fmaf(pe1, vf1.w, fmaf(pe2, vf2.w, pe3 * vf3.w))));
        m = mn;
    }
    for (; j < p1; ++j) {
        int2 pr0 = csr_pair[j];
        ushort4 ku0 = *(const ushort4*)(k + (unsigned)pr0.x * 128u + c4);
        ushort4 vu0 = *(const ushort4*)(v + (unsigned)pr0.x * 128u + c4);
        float4 kf0 = bf4_to_f4(ku0);
        float d0 = kf0.x * qv.x + kf0.y * qv.y + kf0.z * qv.z + kf0.w * qv.w;
        d0 += __shfl_xor(d0, 1); d0 += __shfl_xor(d0, 2); d0 += __shfl_xor(d0, 4);
        float al0 = fmaf(__int_as_float(pr0.y), qwe, d0);
        float mn = fmaxf(m, al0);
        float sc = exp2_hw(m - mn);
        float pe0 = exp2_hw(al0 - mn);
        float4 vf0 = bf4_to_f4(vu0);
        l = fmaf(l, sc, pe0);
        sae = fmaf(sae, sc, pe0 * __int_as_float(pr0.y));
        acc.x = fmaf(acc.x, sc, pe0 * vf0.x);
        acc.y = fmaf(acc.y, sc, pe0 * vf0.y);
        acc.z = fmaf(acc.z, sc, pe0 * vf0.z);
        acc.w = fmaf(acc.w, sc, pe0 * vf0.w);
        m = mn;
    }

    float inv = 1.f / (l + 1e-16f);
    float4 sk = *(const float4*)(skip + (size_t)node * 128 + c4);
    float o0 = fmaxf(fmaf(fmaf(sae, we4.x, acc.x), inv, sk.x), 0.f);
    float o1 = fmaxf(fmaf(fmaf(sae, we4.y, acc.y), inv, sk.y), 0.f);
    float o2 = fmaxf(fmaf(fmaf(sae, we4.z, acc.z), inv, sk.z), 0.f);
    float o3 = fmaxf(fmaf(fmaf(sae, we4.w, acc.w), inv, sk.w), 0.f);
    if (BF16OUT) {
        ushort4 o;
        o.x = f2bf(o0); o.y = f2bf(o1); o.z = f2bf(o2); o.w = f2bf(o3);
        *(ushort4*)((unsigned short*)outp + (size_t)node * 128 + c4) = o;
    } else {
        *(float4*)((float*)outp + (size_t)node * 128 + c4) =
            make_float4(o0, o1, o2, o3);
    }
}

extern "C" void kernel_launch(void* const* d_in, const int* in_sizes, int n_in,
                              void* d_out, int out_size, void* d_ws, size_t ws_size,
                              hipStream_t stream)
{
    const float* x   = (const float*)d_in[0];
    const int*   ei  = (const int*)d_in[1];
    const float* ea  = (const float*)d_in[2];
    const float* Wq1 = (const float*)d_in[3];  const float* bq1 = (const float*)d_in[4];
    const float* Wk1 = (const float*)d_in[5];  const float* bk1 = (const float*)d_in[6];
    const float* Wv1 = (const float*)d_in[7];  const float* bv1 = (const float*)d_in[8];
    const float* We1 = (const float*)d_in[9];
    const float* Ws1 = (const float*)d_in[10]; const float* bs1 = (const float*)d_in[11];
    const float* Wq2 = (const float*)d_in[12]; const float* bq2 = (const float*)d_in[13];
    const float* Wk2 = (const float*)d_in[14]; const float* bk2 = (const float*)d_in[15];
    const float* Wv2 = (const float*)d_in[16]; const float* bv2 = (const float*)d_in[17];
    const float* We2 = (const float*)d_in[18];
    const float* Ws2 = (const float*)d_in[19]; const float* bs2 = (const float*)d_in[20];

    const int N = in_sizes[0] / 128;
    const int E = in_sizes[1] / 2;
    const int* src = ei;
    const int* dst = ei + E;
    float* outf = (float*)d_out;

    // workspace layout
    unsigned short* q  = (unsigned short*)d_ws;          // N*128 bf16
    unsigned short* k  = q + (size_t)N * 128;
    unsigned short* v  = k + (size_t)N * 128;
    float*          s  = (float*)(v + (size_t)N * 128);  // N*128 f32 skip
    unsigned short* xb = (unsigned short*)(s + (size_t)N * 128); // bf16 h (layer1 out)
    unsigned short* pk = xb + (size_t)N * 128;           // 131072 (both layers)
    int*   row_ptr = (int*)(pk + 131072);                // N+1
    int*   deg     = row_ptr + (N + 1);
    int*   incl    = deg + N;
    int*   cursor  = incl + N;
    int*   bsum    = cursor + N;                         // 256
    int2*  csr_pair = (int2*)(bsum + 256 + 1);           // E pairs (8B align ok: offset even)

    // ensure 8-byte alignment for csr_pair
    csr_pair = (int2*)(((uintptr_t)(bsum + 256) + 7) & ~(uintptr_t)7);

    const int gE   = (E + TPB - 1) / TPB;
    const int nb   = (N + 1023) / 1024;
    const int gN8  = (N + 7) / 8;
    const int gG   = (N + 127) / 128;
    const dim3 gGd(gG, 4);

    // ---- CSR build (shared by both layers) ----
    hipMemsetAsync(deg, 0, (size_t)N * sizeof(int), stream);
    hist_k<<<gE, TPB, 0, stream>>>(dst, deg, E);
    scan_a_k<<<nb, TPB, 0, stream>>>(deg, N, incl, bsum);
    scan_b_k<<<1, TPB, 0, stream>>>(bsum, nb);
    finalize_k<<<nb, TPB, 0, stream>>>(incl, deg, bsum, N, row_ptr, cursor);
    scatter_k<<<gE, TPB, 0, stream>>>(src, dst, ea, cursor, csr_pair, E);

    // ---- weight prepack (both layers) ----
    prepack_k<<<131072 / TPB, TPB, 0, stream>>>(Wq1, Wk1, Wv1, Ws1,
                                                Wq2, Wk2, Wv2, Ws2, pk);

    // ---- layer 1 (A = fp32 x, converted inline) ----
    gemm_mfma_k<true><<<gGd, TPB, 0, stream>>>(x, N, pk, bq1, bk1, bv1, bs1,
                                               q, k, v, s);
    node_attn_k<true><<<gN8, TPB, 0, stream>>>(q, k, v, s, We1, row_ptr, csr_pair,
                                               xb, N);
    // ---- layer 2 (A = bf16 h) ----
    gemm_mfma_k<false><<<gGd, TPB, 0, stream>>>(xb, N, pk + 65536, bq2, bk2, bv2, bs2,
                                                q, k, v, s);
    node_attn_k<false><<<gN8, TPB, 0, stream>>>(q, k, v, s, We2, row_ptr, csr_pair,
                                                outf, N);
}

// Round 7
// 312.783 us; speedup vs baseline: 1.0869x; 1.0100x over previous
//
#include <hip/hip_runtime.h>

// TransformerConv x2 on MI355X — MFMA GEMM + 16-lane-per-node gather attention.
// N=50000, E=800000, H=4, C=32, D=128.

#define TPB 256

typedef __attribute__((ext_vector_type(8))) short short8v;
typedef __attribute__((ext_vector_type(8))) unsigned short ushort8v;
typedef __attribute__((ext_vector_type(4))) float f32x4;

__device__ __forceinline__ unsigned short f2bf(float f) {
    unsigned u = __float_as_uint(f);
    u = (u + 0x7FFFu + ((u >> 16) & 1u)) >> 16;
    return (unsigned short)u;
}
__device__ __forceinline__ float bf2f(unsigned short s) {
    return __uint_as_float((unsigned)s << 16);
}
__device__ __forceinline__ float exp2_hw(float x) {
    float r;
    asm("v_exp_f32 %0, %1" : "=v"(r) : "v"(x));
    return r;
}

// ---- pack 8 weight matrices (both layers) into MFMA B-fragment layout ----
__global__ void __launch_bounds__(TPB) prepack_k(
    const float* __restrict__ Wq1, const float* __restrict__ Wk1,
    const float* __restrict__ Wv1, const float* __restrict__ Ws1,
    const float* __restrict__ Wq2, const float* __restrict__ Wk2,
    const float* __restrict__ Wv2, const float* __restrict__ Ws2,
    unsigned short* __restrict__ pack)
{
    int i = blockIdx.x * TPB + threadIdx.x;   // 131072 total
    int j = i & 7, l = (i >> 3) & 63, t = (i >> 9) & 3, c = (i >> 11) & 7, g = (i >> 14) & 7;
    const float* Wt[8] = {Wq1, Wk1, Wv1, Ws1, Wq2, Wk2, Wv2, Ws2};
    const float* W = Wt[g];
    int kk = t * 32 + (l >> 4) * 8 + j;
    int nn = c * 16 + (l & 15);
    pack[i] = f2bf(W[kk * 128 + nn]);
}

// ---- MFMA GEMM: g = blockIdx.y in {q,k,v} -> bf16 out, g==3 (skip) -> fp32 ----
template <bool AF32>
__global__ void __launch_bounds__(TPB) gemm_mfma_k(
    const void* __restrict__ Av, int M,
    const unsigned short* __restrict__ pack,
    const float* __restrict__ bq, const float* __restrict__ bk,
    const float* __restrict__ bv, const float* __restrict__ bs,
    unsigned short* __restrict__ oq, unsigned short* __restrict__ ok,
    unsigned short* __restrict__ ov, float* __restrict__ os)
{
    const int g = blockIdx.y;
    const int row0 = blockIdx.x * 128;
    const int wv = threadIdx.x >> 6;
    const int lane = threadIdx.x & 63;
    const int rbase = row0 + wv * 32;
    const int rlo = lane & 15;
    const int kg = (lane >> 4) * 8;
    const int rof = (lane >> 4) * 4;

    const short8v z8 = {0, 0, 0, 0, 0, 0, 0, 0};
    short8v a[2][4];
#pragma unroll
    for (int m = 0; m < 2; ++m) {
        int row = rbase + m * 16 + rlo;
        if (row >= M) {
#pragma unroll
            for (int t = 0; t < 4; ++t) a[m][t] = z8;
        } else if (AF32) {
            const float* Af = (const float*)Av + (size_t)row * 128 + kg;
#pragma unroll
            for (int t = 0; t < 4; ++t) {
                float4 lo = *(const float4*)(Af + t * 32);
                float4 hi = *(const float4*)(Af + t * 32 + 4);
                short8v p;
                p[0] = (short)f2bf(lo.x); p[1] = (short)f2bf(lo.y);
                p[2] = (short)f2bf(lo.z); p[3] = (short)f2bf(lo.w);
                p[4] = (short)f2bf(hi.x); p[5] = (short)f2bf(hi.y);
                p[6] = (short)f2bf(hi.z); p[7] = (short)f2bf(hi.w);
                a[m][t] = p;
            }
        } else {
            const unsigned short* Ab = (const unsigned short*)Av + (size_t)row * 128 + kg;
#pragma unroll
            for (int t = 0; t < 4; ++t)
                a[m][t] = *(const short8v*)(Ab + t * 32);
        }
    }

    f32x4 acc[2][8];
#pragma unroll
    for (int m = 0; m < 2; ++m)
#pragma unroll
        for (int c = 0; c < 8; ++c)
            acc[m][c] = (f32x4){0.f, 0.f, 0.f, 0.f};

    const unsigned short* bp = pack + (size_t)g * (8 * 4 * 512);
#pragma unroll
    for (int c = 0; c < 8; ++c) {
        short8v b[4];
#pragma unroll
        for (int t = 0; t < 4; ++t)
            b[t] = *(const short8v*)(bp + (c * 4 + t) * 512 + lane * 8);
#pragma unroll
        for (int t = 0; t < 4; ++t) {
            acc[0][c] = __builtin_amdgcn_mfma_f32_16x16x32_bf16(a[0][t], b[t], acc[0][c], 0, 0, 0);
            acc[1][c] = __builtin_amdgcn_mfma_f32_16x16x32_bf16(a[1][t], b[t], acc[1][c], 0, 0, 0);
        }
    }

    const float* bias = g == 0 ? bq : (g == 1 ? bk : (g == 2 ? bv : bs));
    if (g == 3) {
#pragma unroll
        for (int c = 0; c < 8; ++c) {
            float bb = bias[c * 16 + rlo];
#pragma unroll
            for (int m = 0; m < 2; ++m)
#pragma unroll
                for (int j = 0; j < 4; ++j) {
                    int row = rbase + m * 16 + rof + j;
                    if (row < M) os[(size_t)row * 128 + c * 16 + rlo] = acc[m][c][j] + bb;
                }
        }
    } else {
        unsigned short* out = g == 0 ? oq : (g == 1 ? ok : ov);
#pragma unroll
        for (int c = 0; c < 8; ++c) {
            float bb = bias[c * 16 + rlo];
#pragma unroll
            for (int m = 0; m < 2; ++m)
#pragma unroll
                for (int j = 0; j < 4; ++j) {
                    int row = rbase + m * 16 + rof + j;
                    if (row < M) out[(size_t)row * 128 + c * 16 + rlo] = f2bf(acc[m][c][j] + bb);
                }
        }
    }
}

// ---------------- CSR build ----------------
__global__ void __launch_bounds__(TPB) hist_k(const int* __restrict__ dst,
                                              int* __restrict__ deg, int E)
{
    int e = blockIdx.x * TPB + threadIdx.x;
    if (e < E) atomicAdd(&deg[dst[e]], 1);
}

__global__ void __launch_bounds__(TPB) scan_a_k(const int* __restrict__ deg, int n,
                                                int* __restrict__ incl,
                                                int* __restrict__ bsum)
{
    __shared__ int ts[TPB];
    const int base = blockIdx.x * 1024;
    int vals[4], s = 0;
#pragma unroll
    for (int j = 0; j < 4; ++j) {
        int i = base + threadIdx.x * 4 + j;
        vals[j] = (i < n) ? deg[i] : 0;
        s += vals[j];
    }
    ts[threadIdx.x] = s;
    __syncthreads();
    for (int off = 1; off < TPB; off <<= 1) {
        int u = (threadIdx.x >= off) ? ts[threadIdx.x - off] : 0;
        __syncthreads();
        ts[threadIdx.x] += u;
        __syncthreads();
    }
    int run = ts[threadIdx.x] - s;
#pragma unroll
    for (int j = 0; j < 4; ++j) {
        run += vals[j];
        int i = base + threadIdx.x * 4 + j;
        if (i < n) incl[i] = run;
    }
    if (threadIdx.x == TPB - 1) bsum[blockIdx.x] = ts[TPB - 1];
}

__global__ void __launch_bounds__(TPB) scan_b_k(int* __restrict__ bsum, int nb)
{
    __shared__ int ts[TPB];
    int t = threadIdx.x;
    int v = (t < nb) ? bsum[t] : 0;
    ts[t] = v;
    __syncthreads();
    for (int off = 1; off < TPB; off <<= 1) {
        int u = (t >= off) ? ts[t - off] : 0;
        __syncthreads();
        ts[t] += u;
        __syncthreads();
    }
    if (t < nb) bsum[t] = ts[t] - v;
}

__global__ void __launch_bounds__(TPB) finalize_k(const int* __restrict__ incl,
                                                  const int* __restrict__ deg,
                                                  const int* __restrict__ bsum, int n,
                                                  int* __restrict__ row_ptr,
                                                  int* __restrict__ cursor)
{
    const int base = blockIdx.x * 1024;
    const int boff = bsum[blockIdx.x];
#pragma unroll
    for (int j = 0; j < 4; ++j) {
        int i = base + threadIdx.x * 4 + j;
        if (i < n) {
            int iv = incl[i] + boff;
            int st = iv - deg[i];
            row_ptr[i] = st;
            cursor[i] = st;
            if (i == n - 1) row_ptr[n] = iv;
        }
    }
}

__global__ void __launch_bounds__(TPB) scatter_k(
    const int* __restrict__ src, const int* __restrict__ dst,
    const float* __restrict__ ea, int* __restrict__ cursor,
    int2* __restrict__ csr_pair, int E)
{
    int e = blockIdx.x * TPB + threadIdx.x;
    if (e >= E) return;
    int pos = atomicAdd(&cursor[dst[e]], 1);
    csr_pair[pos] = make_int2(src[e], __float_as_int(ea[e]));
}

// ---- fused gather attention: 16 lanes/node, 4 nodes/wave, 16-B gathers ----
// Lane owns comps 8*l16..+7; head = l16>>2 (4 lanes/head). Dot reduce = 2 xor
// shfl. Tail edges masked via index clamp + alpha = -inf (pe -> 0).
template <bool BF16OUT>
__global__ void __launch_bounds__(TPB) node_attn_k(
    const unsigned short* __restrict__ q, const unsigned short* __restrict__ k,
    const unsigned short* __restrict__ v, const float* __restrict__ skip,
    const float* __restrict__ We,
    const int* __restrict__ row_ptr, const int2* __restrict__ csr_pair,
    void* __restrict__ outp, int n)
{
    const int node = blockIdx.x * 16 + (threadIdx.x >> 4);
    if (node >= n) return;
    const int l16 = threadIdx.x & 15;
    const int c8 = l16 * 8;

    const float C2 = 0.17677669529663687f * 1.44269504088896f; // 1/sqrt(32)*log2e

    float we8[8], qv[8];
    {
        float4 wlo = *(const float4*)(We + c8);
        float4 whi = *(const float4*)(We + c8 + 4);
        we8[0] = wlo.x; we8[1] = wlo.y; we8[2] = wlo.z; we8[3] = wlo.w;
        we8[4] = whi.x; we8[5] = whi.y; we8[6] = whi.z; we8[7] = whi.w;
        ushort8v qu = *(const ushort8v*)(q + (size_t)node * 128 + c8);
#pragma unroll
        for (int i = 0; i < 8; ++i) qv[i] = bf2f((unsigned short)qu[i]) * C2;
    }

    float qwe = 0.f;
#pragma unroll
    for (int i = 0; i < 8; ++i) qwe = fmaf(qv[i], we8[i], qwe);
    qwe += __shfl_xor(qwe, 1);
    qwe += __shfl_xor(qwe, 2);

    const int p0 = row_ptr[node], p1 = row_ptr[node + 1];

    float m = -3.4e38f, l = 0.f, sae = 0.f;
    float acc[8];
#pragma unroll
    for (int i = 0; i < 8; ++i) acc[i] = 0.f;

    for (int j = p0; j < p1; j += 4) {
        const int last = p1 - 1;
        int2 pr0 = csr_pair[j];
        int2 pr1 = csr_pair[min(j + 1, last)];
        int2 pr2 = csr_pair[min(j + 2, last)];
        int2 pr3 = csr_pair[min(j + 3, last)];
        ushort8v ku0 = *(const ushort8v*)(k + (unsigned)pr0.x * 128u + c8);
        ushort8v ku1 = *(const ushort8v*)(k + (unsigned)pr1.x * 128u + c8);
        ushort8v ku2 = *(const ushort8v*)(k + (unsigned)pr2.x * 128u + c8);
        ushort8v ku3 = *(const ushort8v*)(k + (unsigned)pr3.x * 128u + c8);
        ushort8v vu0 = *(const ushort8v*)(v + (unsigned)pr0.x * 128u + c8);
        ushort8v vu1 = *(const ushort8v*)(v + (unsigned)pr1.x * 128u + c8);
        ushort8v vu2 = *(const ushort8v*)(v + (unsigned)pr2.x * 128u + c8);
        ushort8v vu3 = *(const ushort8v*)(v + (unsigned)pr3.x * 128u + c8);

        float d0 = 0.f, d1 = 0.f, d2 = 0.f, d3 = 0.f;
#pragma unroll
        for (int i = 0; i < 8; ++i) {
            d0 = fmaf(bf2f((unsigned short)ku0[i]), qv[i], d0);
            d1 = fmaf(bf2f((unsigned short)ku1[i]), qv[i], d1);
            d2 = fmaf(bf2f((unsigned short)ku2[i]), qv[i], d2);
            d3 = fmaf(bf2f((unsigned short)ku3[i]), qv[i], d3);
        }
        d0 += __shfl_xor(d0, 1); d0 += __shfl_xor(d0, 2);
        d1 += __shfl_xor(d1, 1); d1 += __shfl_xor(d1, 2);
        d2 += __shfl_xor(d2, 1); d2 += __shfl_xor(d2, 2);
        d3 += __shfl_xor(d3, 1); d3 += __shfl_xor(d3, 2);

        float ea0 = __int_as_float(pr0.y), ea1 = __int_as_float(pr1.y);
        float ea2 = __int_as_float(pr2.y), ea3 = __int_as_float(pr3.y);
        float al0 = fmaf(ea0, qwe, d0);
        float al1 = (j + 1 < p1) ? fmaf(ea1, qwe, d1) : -3.4e38f;
        float al2 = (j + 2 < p1) ? fmaf(ea2, qwe, d2) : -3.4e38f;
        float al3 = (j + 3 < p1) ? fmaf(ea3, qwe, d3) : -3.4e38f;

        float mn = fmaxf(m, fmaxf(fmaxf(al0, al1), fmaxf(al2, al3)));
        float sc = exp2_hw(m - mn);
        float pe0 = exp2_hw(al0 - mn), pe1 = exp2_hw(al1 - mn);
        float pe2 = exp2_hw(al2 - mn), pe3 = exp2_hw(al3 - mn);

        l = fmaf(l, sc, (pe0 + pe1) + (pe2 + pe3));
        sae = fmaf(sae, sc, fmaf(pe3, ea3, fmaf(pe2, ea2, fmaf(pe1, ea1, pe0 * ea0))));
#pragma unroll
        for (int i = 0; i < 8; ++i) {
            float mv = fmaf(pe0, bf2f((unsigned short)vu0[i]),
                       fmaf(pe1, bf2f((unsigned short)vu1[i]),
                       fmaf(pe2, bf2f((unsigned short)vu2[i]),
                            pe3 * bf2f((unsigned short)vu3[i]))));
            acc[i] = fmaf(acc[i], sc, mv);
        }
        m = mn;
    }

    float inv = 1.f / (l + 1e-16f);
    float4 sklo = *(const float4*)(skip + (size_t)node * 128 + c8);
    float4 skhi = *(const float4*)(skip + (size_t)node * 128 + c8 + 4);
    float sk[8] = {sklo.x, sklo.y, sklo.z, sklo.w, skhi.x, skhi.y, skhi.z, skhi.w};
    float o[8];
#pragma unroll
    for (int i = 0; i < 8; ++i)
        o[i] = fmaxf(fmaf(fmaf(sae, we8[i], acc[i]), inv, sk[i]), 0.f);

    if (BF16OUT) {
        ushort8v ov;
#pragma unroll
        for (int i = 0; i < 8; ++i) ov[i] = f2bf(o[i]);
        *(ushort8v*)((unsigned short*)outp + (size_t)node * 128 + c8) = ov;
    } else {
        float* op = (float*)outp + (size_t)node * 128 + c8;
        *(float4*)op = make_float4(o[0], o[1], o[2], o[3]);
        *(float4*)(op + 4) = make_float4(o[4], o[5], o[6], o[7]);
    }
}

extern "C" void kernel_launch(void* const* d_in, const int* in_sizes, int n_in,
                              void* d_out, int out_size, void* d_ws, size_t ws_size,
                              hipStream_t stream)
{
    const float* x   = (const float*)d_in[0];
    const int*   ei  = (const int*)d_in[1];
    const float* ea  = (const float*)d_in[2];
    const float* Wq1 = (const float*)d_in[3];  const float* bq1 = (const float*)d_in[4];
    const float* Wk1 = (const float*)d_in[5];  const float* bk1 = (const float*)d_in[6];
    const float* Wv1 = (const float*)d_in[7];  const float* bv1 = (const float*)d_in[8];
    const float* We1 = (const float*)d_in[9];
    const float* Ws1 = (const float*)d_in[10]; const float* bs1 = (const float*)d_in[11];
    const float* Wq2 = (const float*)d_in[12]; const float* bq2 = (const float*)d_in[13];
    const float* Wk2 = (const float*)d_in[14]; const float* bk2 = (const float*)d_in[15];
    const float* Wv2 = (const float*)d_in[16]; const float* bv2 = (const float*)d_in[17];
    const float* We2 = (const float*)d_in[18];
    const float* Ws2 = (const float*)d_in[19]; const float* bs2 = (const float*)d_in[20];

    const int N = in_sizes[0] / 128;
    const int E = in_sizes[1] / 2;
    const int* src = ei;
    const int* dst = ei + E;
    float* outf = (float*)d_out;

    // workspace layout
    unsigned short* q  = (unsigned short*)d_ws;          // N*128 bf16
    unsigned short* k  = q + (size_t)N * 128;
    unsigned short* v  = k + (size_t)N * 128;
    float*          s  = (float*)(v + (size_t)N * 128);  // N*128 f32 skip
    unsigned short* xb = (unsigned short*)(s + (size_t)N * 128); // bf16 h (layer1 out)
    unsigned short* pk = xb + (size_t)N * 128;           // 131072 (both layers)
    int*   row_ptr = (int*)(pk + 131072);                // N+1
    int*   deg     = row_ptr + (N + 1);
    int*   incl    = deg + N;
    int*   cursor  = incl + N;
    int*   bsum    = cursor + N;                         // 256
    int2*  csr_pair = (int2*)(((uintptr_t)(bsum + 256) + 7) & ~(uintptr_t)7); // E pairs

    const int gE   = (E + TPB - 1) / TPB;
    const int nb   = (N + 1023) / 1024;
    const int gN16 = (N + 15) / 16;
    const int gG   = (N + 127) / 128;
    const dim3 gGd(gG, 4);

    // ---- CSR build (shared by both layers) ----
    hipMemsetAsync(deg, 0, (size_t)N * sizeof(int), stream);
    hist_k<<<gE, TPB, 0, stream>>>(dst, deg, E);
    scan_a_k<<<nb, TPB, 0, stream>>>(deg, N, incl, bsum);
    scan_b_k<<<1, TPB, 0, stream>>>(bsum, nb);
    finalize_k<<<nb, TPB, 0, stream>>>(incl, deg, bsum, N, row_ptr, cursor);
    scatter_k<<<gE, TPB, 0, stream>>>(src, dst, ea, cursor, csr_pair, E);

    // ---- weight prepack (both layers) ----
    prepack_k<<<131072 / TPB, TPB, 0, stream>>>(Wq1, Wk1, Wv1, Ws1,
                                                Wq2, Wk2, Wv2, Ws2, pk);

    // ---- layer 1 (A = fp32 x, converted inline) ----
    gemm_mfma_k<true><<<gGd, TPB, 0, stream>>>(x, N, pk, bq1, bk1, bv1, bs1,
                                               q, k, v, s);
    node_attn_k<true><<<gN16, TPB, 0, stream>>>(q, k, v, s, We1, row_ptr, csr_pair,
                                                xb, N);
    // ---- layer 2 (A = bf16 h) ----
    gemm_mfma_k<false><<<gGd, TPB, 0, stream>>>(xb, N, pk + 65536, bq2, bk2, bv2, bs2,
                                                q, k, v, s);
    node_attn_k<false><<<gN16, TPB, 0, stream>>>(q, k, v, s, We2, row_ptr, csr_pair,
                                                 outf, N);
}

// Round 8
// 311.302 us; speedup vs baseline: 1.0921x; 1.0048x over previous
//
#include <hip/hip_runtime.h>

// TransformerConv x2 on MI355X — MFMA GEMM + pipelined 16-lane gather attention.
// N=50000, E=800000, H=4, C=32, D=128.

#define TPB 256

typedef __attribute__((ext_vector_type(8))) short short8v;
typedef __attribute__((ext_vector_type(8))) unsigned short ushort8v;
typedef __attribute__((ext_vector_type(4))) float f32x4;

__device__ __forceinline__ unsigned short f2bf(float f) {
    unsigned u = __float_as_uint(f);
    u = (u + 0x7FFFu + ((u >> 16) & 1u)) >> 16;
    return (unsigned short)u;
}
__device__ __forceinline__ float bf2f(unsigned short s) {
    return __uint_as_float((unsigned)s << 16);
}
__device__ __forceinline__ float exp2_hw(float x) {
    float r;
    asm("v_exp_f32 %0, %1" : "=v"(r) : "v"(x));
    return r;
}

// ---- fp32 -> bf16 convert (vectorized) ----
__global__ void __launch_bounds__(TPB) cvt_bf16_k(const float* __restrict__ in,
                                                  unsigned short* __restrict__ out,
                                                  int n4)
{
    int i = blockIdx.x * TPB + threadIdx.x;
    if (i >= n4) return;
    float4 v = *(const float4*)(in + (size_t)i * 4);
    ushort4 o;
    o.x = f2bf(v.x); o.y = f2bf(v.y); o.z = f2bf(v.z); o.w = f2bf(v.w);
    *(ushort4*)(out + (size_t)i * 4) = o;
}

// ---- pack 8 weight matrices (both layers) into MFMA B-fragment layout ----
__global__ void __launch_bounds__(TPB) prepack_k(
    const float* __restrict__ Wq1, const float* __restrict__ Wk1,
    const float* __restrict__ Wv1, const float* __restrict__ Ws1,
    const float* __restrict__ Wq2, const float* __restrict__ Wk2,
    const float* __restrict__ Wv2, const float* __restrict__ Ws2,
    unsigned short* __restrict__ pack)
{
    int i = blockIdx.x * TPB + threadIdx.x;   // 131072 total
    int j = i & 7, l = (i >> 3) & 63, t = (i >> 9) & 3, c = (i >> 11) & 7, g = (i >> 14) & 7;
    const float* Wt[8] = {Wq1, Wk1, Wv1, Ws1, Wq2, Wk2, Wv2, Ws2};
    const float* W = Wt[g];
    int kk = t * 32 + (l >> 4) * 8 + j;
    int nn = c * 16 + (l & 15);
    pack[i] = f2bf(W[kk * 128 + nn]);
}

// ---- MFMA GEMM: g = blockIdx.y in {q,k,v} -> bf16 out, g==3 (skip) -> fp32 ----
__global__ void __launch_bounds__(TPB) gemm_mfma_k(
    const unsigned short* __restrict__ A, int M,
    const unsigned short* __restrict__ pack,
    const float* __restrict__ bq, const float* __restrict__ bk,
    const float* __restrict__ bv, const float* __restrict__ bs,
    unsigned short* __restrict__ oq, unsigned short* __restrict__ ok,
    unsigned short* __restrict__ ov, float* __restrict__ os)
{
    const int g = blockIdx.y;
    const int row0 = blockIdx.x * 128;
    const int wv = threadIdx.x >> 6;
    const int lane = threadIdx.x & 63;
    const int rbase = row0 + wv * 32;
    const int rlo = lane & 15;
    const int kg = (lane >> 4) * 8;
    const int rof = (lane >> 4) * 4;

    const short8v z8 = {0, 0, 0, 0, 0, 0, 0, 0};
    short8v a[2][4];
#pragma unroll
    for (int m = 0; m < 2; ++m) {
        int row = rbase + m * 16 + rlo;
#pragma unroll
        for (int t = 0; t < 4; ++t)
            a[m][t] = (row < M) ? *(const short8v*)(A + (size_t)row * 128 + t * 32 + kg)
                                : z8;
    }

    f32x4 acc[2][8];
#pragma unroll
    for (int m = 0; m < 2; ++m)
#pragma unroll
        for (int c = 0; c < 8; ++c)
            acc[m][c] = (f32x4){0.f, 0.f, 0.f, 0.f};

    const unsigned short* bp = pack + (size_t)g * (8 * 4 * 512);
#pragma unroll
    for (int c = 0; c < 8; ++c) {
        short8v b[4];
#pragma unroll
        for (int t = 0; t < 4; ++t)
            b[t] = *(const short8v*)(bp + (c * 4 + t) * 512 + lane * 8);
#pragma unroll
        for (int t = 0; t < 4; ++t) {
            acc[0][c] = __builtin_amdgcn_mfma_f32_16x16x32_bf16(a[0][t], b[t], acc[0][c], 0, 0, 0);
            acc[1][c] = __builtin_amdgcn_mfma_f32_16x16x32_bf16(a[1][t], b[t], acc[1][c], 0, 0, 0);
        }
    }

    const float* bias = g == 0 ? bq : (g == 1 ? bk : (g == 2 ? bv : bs));
    if (g == 3) {
#pragma unroll
        for (int c = 0; c < 8; ++c) {
            float bb = bias[c * 16 + rlo];
#pragma unroll
            for (int m = 0; m < 2; ++m)
#pragma unroll
                for (int j = 0; j < 4; ++j) {
                    int row = rbase + m * 16 + rof + j;
                    if (row < M) os[(size_t)row * 128 + c * 16 + rlo] = acc[m][c][j] + bb;
                }
        }
    } else {
        unsigned short* out = g == 0 ? oq : (g == 1 ? ok : ov);
#pragma unroll
        for (int c = 0; c < 8; ++c) {
            float bb = bias[c * 16 + rlo];
#pragma unroll
            for (int m = 0; m < 2; ++m)
#pragma unroll
                for (int j = 0; j < 4; ++j) {
                    int row = rbase + m * 16 + rof + j;
                    if (row < M) out[(size_t)row * 128 + c * 16 + rlo] = f2bf(acc[m][c][j] + bb);
                }
        }
    }
}

// ---------------- CSR build ----------------
__global__ void __launch_bounds__(TPB) hist_k(const int* __restrict__ dst,
                                              int* __restrict__ deg, int E)
{
    int e = blockIdx.x * TPB + threadIdx.x;
    if (e < E) atomicAdd(&deg[dst[e]], 1);
}

__global__ void __launch_bounds__(TPB) scan_a_k(const int* __restrict__ deg, int n,
                                                int* __restrict__ incl,
                                                int* __restrict__ bsum)
{
    __shared__ int ts[TPB];
    const int base = blockIdx.x * 1024;
    int vals[4], s = 0;
#pragma unroll
    for (int j = 0; j < 4; ++j) {
        int i = base + threadIdx.x * 4 + j;
        vals[j] = (i < n) ? deg[i] : 0;
        s += vals[j];
    }
    ts[threadIdx.x] = s;
    __syncthreads();
    for (int off = 1; off < TPB; off <<= 1) {
        int u = (threadIdx.x >= off) ? ts[threadIdx.x - off] : 0;
        __syncthreads();
        ts[threadIdx.x] += u;
        __syncthreads();
    }
    int run = ts[threadIdx.x] - s;
#pragma unroll
    for (int j = 0; j < 4; ++j) {
        run += vals[j];
        int i = base + threadIdx.x * 4 + j;
        if (i < n) incl[i] = run;
    }
    if (threadIdx.x == TPB - 1) bsum[blockIdx.x] = ts[TPB - 1];
}

__global__ void __launch_bounds__(TPB) scan_b_k(int* __restrict__ bsum, int nb)
{
    __shared__ int ts[TPB];
    int t = threadIdx.x;
    int v = (t < nb) ? bsum[t] : 0;
    ts[t] = v;
    __syncthreads();
    for (int off = 1; off < TPB; off <<= 1) {
        int u = (t >= off) ? ts[t - off] : 0;
        __syncthreads();
        ts[t] += u;
        __syncthreads();
    }
    if (t < nb) bsum[t] = ts[t] - v;
}

__global__ void __launch_bounds__(TPB) finalize_k(const int* __restrict__ incl,
                                                  const int* __restrict__ deg,
                                                  const int* __restrict__ bsum, int n,
                                                  int* __restrict__ row_ptr,
                                                  int* __restrict__ cursor)
{
    const int base = blockIdx.x * 1024;
    const int boff = bsum[blockIdx.x];
#pragma unroll
    for (int j = 0; j < 4; ++j) {
        int i = base + threadIdx.x * 4 + j;
        if (i < n) {
            int iv = incl[i] + boff;
            int st = iv - deg[i];
            row_ptr[i] = st;
            cursor[i] = st;
            if (i == n - 1) row_ptr[n] = iv;
        }
    }
}

__global__ void __launch_bounds__(TPB) scatter_k(
    const int* __restrict__ src, const int* __restrict__ dst,
    const float* __restrict__ ea, int* __restrict__ cursor,
    int2* __restrict__ csr_pair, int E)
{
    int e = blockIdx.x * TPB + threadIdx.x;
    if (e >= E) return;
    int pos = atomicAdd(&cursor[dst[e]], 1);
    csr_pair[pos] = make_int2(src[e], __float_as_int(ea[e]));
}

// ---- pipelined gather attention: 16 lanes/node, 2-stage register ring ----
struct Stage {
    int2 p[4];
    ushort8v ku[4], vu[4];
};

__device__ __forceinline__ void attn_step(
    Stage& cur, Stage& nxt, int j, int p1, int last,
    const int2* __restrict__ csr_pair,
    const unsigned short* __restrict__ k, const unsigned short* __restrict__ v,
    int c8, const float* qv, float qwe,
    float& m, float& l, float& sae, float* acc)
{
    // extract current edge scalars, then recycle cur.p for pairs j+8
    float ea0 = __int_as_float(cur.p[0].y), ea1 = __int_as_float(cur.p[1].y);
    float ea2 = __int_as_float(cur.p[2].y), ea3 = __int_as_float(cur.p[3].y);
#pragma unroll
    for (int t = 0; t < 4; ++t) cur.p[t] = csr_pair[min(j + 8 + t, last)];

    // prefetch next iteration's k/v (addresses ready from nxt.p)
#pragma unroll
    for (int t = 0; t < 4; ++t) {
        nxt.ku[t] = *(const ushort8v*)(k + (unsigned)nxt.p[t].x * 128u + c8);
        nxt.vu[t] = *(const ushort8v*)(v + (unsigned)nxt.p[t].x * 128u + c8);
    }

    // compute on current stage
    float d0 = 0.f, d1 = 0.f, d2 = 0.f, d3 = 0.f;
#pragma unroll
    for (int i = 0; i < 8; ++i) {
        d0 = fmaf(bf2f((unsigned short)cur.ku[0][i]), qv[i], d0);
        d1 = fmaf(bf2f((unsigned short)cur.ku[1][i]), qv[i], d1);
        d2 = fmaf(bf2f((unsigned short)cur.ku[2][i]), qv[i], d2);
        d3 = fmaf(bf2f((unsigned short)cur.ku[3][i]), qv[i], d3);
    }
    d0 += __shfl_xor(d0, 1); d0 += __shfl_xor(d0, 2);
    d1 += __shfl_xor(d1, 1); d1 += __shfl_xor(d1, 2);
    d2 += __shfl_xor(d2, 1); d2 += __shfl_xor(d2, 2);
    d3 += __shfl_xor(d3, 1); d3 += __shfl_xor(d3, 2);

    float al0 = fmaf(ea0, qwe, d0);
    float al1 = (j + 1 < p1) ? fmaf(ea1, qwe, d1) : -3.4e38f;
    float al2 = (j + 2 < p1) ? fmaf(ea2, qwe, d2) : -3.4e38f;
    float al3 = (j + 3 < p1) ? fmaf(ea3, qwe, d3) : -3.4e38f;

    float mn = fmaxf(m, fmaxf(fmaxf(al0, al1), fmaxf(al2, al3)));
    float sc = exp2_hw(m - mn);
    float pe0 = exp2_hw(al0 - mn), pe1 = exp2_hw(al1 - mn);
    float pe2 = exp2_hw(al2 - mn), pe3 = exp2_hw(al3 - mn);

    l = fmaf(l, sc, (pe0 + pe1) + (pe2 + pe3));
    sae = fmaf(sae, sc, fmaf(pe3, ea3, fmaf(pe2, ea2, fmaf(pe1, ea1, pe0 * ea0))));
#pragma unroll
    for (int i = 0; i < 8; ++i) {
        float mv = fmaf(pe0, bf2f((unsigned short)cur.vu[0][i]),
                   fmaf(pe1, bf2f((unsigned short)cur.vu[1][i]),
                   fmaf(pe2, bf2f((unsigned short)cur.vu[2][i]),
                        pe3 * bf2f((unsigned short)cur.vu[3][i]))));
        acc[i] = fmaf(acc[i], sc, mv);
    }
    m = mn;
}

template <bool BF16OUT>
__global__ void __launch_bounds__(TPB) node_attn_k(
    const unsigned short* __restrict__ q, const unsigned short* __restrict__ k,
    const unsigned short* __restrict__ v, const float* __restrict__ skip,
    const float* __restrict__ We,
    const int* __restrict__ row_ptr, const int2* __restrict__ csr_pair,
    void* __restrict__ outp, int n)
{
    const int node = blockIdx.x * 16 + (threadIdx.x >> 4);
    if (node >= n) return;
    const int l16 = threadIdx.x & 15;
    const int c8 = l16 * 8;

    const float C2 = 0.17677669529663687f * 1.44269504088896f; // 1/sqrt(32)*log2e

    float qv[8];
    float qwe;
    {
        float4 wlo = *(const float4*)(We + c8);
        float4 whi = *(const float4*)(We + c8 + 4);
        ushort8v qu = *(const ushort8v*)(q + (size_t)node * 128 + c8);
#pragma unroll
        for (int i = 0; i < 8; ++i) qv[i] = bf2f((unsigned short)qu[i]) * C2;
        qwe = qv[0] * wlo.x + qv[1] * wlo.y + qv[2] * wlo.z + qv[3] * wlo.w +
              qv[4] * whi.x + qv[5] * whi.y + qv[6] * whi.z + qv[7] * whi.w;
        qwe += __shfl_xor(qwe, 1);
        qwe += __shfl_xor(qwe, 2);
    }

    const int p0 = row_ptr[node], p1 = row_ptr[node + 1];

    float m = -3.4e38f, l = 0.f, sae = 0.f;
    float acc[8];
#pragma unroll
    for (int i = 0; i < 8; ++i) acc[i] = 0.f;

    if (p0 < p1) {
        const int last = p1 - 1;
        Stage A, B;
#pragma unroll
        for (int t = 0; t < 4; ++t) A.p[t] = csr_pair[min(p0 + t, last)];
#pragma unroll
        for (int t = 0; t < 4; ++t) B.p[t] = csr_pair[min(p0 + 4 + t, last)];
#pragma unroll
        for (int t = 0; t < 4; ++t) {
            A.ku[t] = *(const ushort8v*)(k + (unsigned)A.p[t].x * 128u + c8);
            A.vu[t] = *(const ushort8v*)(v + (unsigned)A.p[t].x * 128u + c8);
        }
        int j = p0;
        for (;;) {
            attn_step(A, B, j, p1, last, csr_pair, k, v, c8, qv, qwe, m, l, sae, acc);
            j += 4; if (j >= p1) break;
            attn_step(B, A, j, p1, last, csr_pair, k, v, c8, qv, qwe, m, l, sae, acc);
            j += 4; if (j >= p1) break;
        }
    }

    float inv = 1.f / (l + 1e-16f);
    float4 wlo = *(const float4*)(We + c8);
    float4 whi = *(const float4*)(We + c8 + 4);
    float we8[8] = {wlo.x, wlo.y, wlo.z, wlo.w, whi.x, whi.y, whi.z, whi.w};
    float4 sklo = *(const float4*)(skip + (size_t)node * 128 + c8);
    float4 skhi = *(const float4*)(skip + (size_t)node * 128 + c8 + 4);
    float sk[8] = {sklo.x, sklo.y, sklo.z, sklo.w, skhi.x, skhi.y, skhi.z, skhi.w};
    float o[8];
#pragma unroll
    for (int i = 0; i < 8; ++i)
        o[i] = fmaxf(fmaf(fmaf(sae, we8[i], acc[i]), inv, sk[i]), 0.f);

    if (BF16OUT) {
        ushort8v ov;
#pragma unroll
        for (int i = 0; i < 8; ++i) ov[i] = f2bf(o[i]);
        *(ushort8v*)((unsigned short*)outp + (size_t)node * 128 + c8) = ov;
    } else {
        float* op = (float*)outp + (size_t)node * 128 + c8;
        *(float4*)op = make_float4(o[0], o[1], o[2], o[3]);
        *(float4*)(op + 4) = make_float4(o[4], o[5], o[6], o[7]);
    }
}

extern "C" void kernel_launch(void* const* d_in, const int* in_sizes, int n_in,
                              void* d_out, int out_size, void* d_ws, size_t ws_size,
                              hipStream_t stream)
{
    const float* x   = (const float*)d_in[0];
    const int*   ei  = (const int*)d_in[1];
    const float* ea  = (const float*)d_in[2];
    const float* Wq1 = (const float*)d_in[3];  const float* bq1 = (const float*)d_in[4];
    const float* Wk1 = (const float*)d_in[5];  const float* bk1 = (const float*)d_in[6];
    const float* Wv1 = (const float*)d_in[7];  const float* bv1 = (const float*)d_in[8];
    const float* We1 = (const float*)d_in[9];
    const float* Ws1 = (const float*)d_in[10]; const float* bs1 = (const float*)d_in[11];
    const float* Wq2 = (const float*)d_in[12]; const float* bq2 = (const float*)d_in[13];
    const float* Wk2 = (const float*)d_in[14]; const float* bk2 = (const float*)d_in[15];
    const float* Wv2 = (const float*)d_in[16]; const float* bv2 = (const float*)d_in[17];
    const float* We2 = (const float*)d_in[18];
    const float* Ws2 = (const float*)d_in[19]; const float* bs2 = (const float*)d_in[20];

    const int N = in_sizes[0] / 128;
    const int E = in_sizes[1] / 2;
    const int* src = ei;
    const int* dst = ei + E;
    float* outf = (float*)d_out;

    // workspace layout
    unsigned short* q  = (unsigned short*)d_ws;          // N*128 bf16
    unsigned short* k  = q + (size_t)N * 128;
    unsigned short* v  = k + (size_t)N * 128;
    float*          s  = (float*)(v + (size_t)N * 128);  // N*128 f32 skip
    unsigned short* xb = (unsigned short*)(s + (size_t)N * 128); // bf16 x / h
    unsigned short* pk = xb + (size_t)N * 128;           // 131072 (both layers)
    int*   row_ptr = (int*)(pk + 131072);                // N+1
    int*   deg     = row_ptr + (N + 1);
    int*   incl    = deg + N;
    int*   cursor  = incl + N;
    int*   bsum    = cursor + N;                         // 256
    int2*  csr_pair = (int2*)(((uintptr_t)(bsum + 256) + 7) & ~(uintptr_t)7); // E pairs

    const int gE   = (E + TPB - 1) / TPB;
    const int nb   = (N + 1023) / 1024;
    const int gN16 = (N + 15) / 16;
    const int gCv  = (N * 128 / 4 + TPB - 1) / TPB;
    const int gG   = (N + 127) / 128;
    const dim3 gGd(gG, 4);

    // ---- CSR build (shared by both layers) ----
    hipMemsetAsync(deg, 0, (size_t)N * sizeof(int), stream);
    hist_k<<<gE, TPB, 0, stream>>>(dst, deg, E);
    scan_a_k<<<nb, TPB, 0, stream>>>(deg, N, incl, bsum);
    scan_b_k<<<1, TPB, 0, stream>>>(bsum, nb);
    finalize_k<<<nb, TPB, 0, stream>>>(incl, deg, bsum, N, row_ptr, cursor);
    scatter_k<<<gE, TPB, 0, stream>>>(src, dst, ea, cursor, csr_pair, E);

    // ---- weight prepack + x convert ----
    prepack_k<<<131072 / TPB, TPB, 0, stream>>>(Wq1, Wk1, Wv1, Ws1,
                                                Wq2, Wk2, Wv2, Ws2, pk);
    cvt_bf16_k<<<gCv, TPB, 0, stream>>>(x, xb, N * 128 / 4);

    // ---- layer 1 ----
    gemm_mfma_k<<<gGd, TPB, 0, stream>>>(xb, N, pk, bq1, bk1, bv1, bs1, q, k, v, s);
    node_attn_k<true><<<gN16, TPB, 0, stream>>>(q, k, v, s, We1, row_ptr, csr_pair,
                                                xb, N);
    // ---- layer 2 ----
    gemm_mfma_k<<<gGd, TPB, 0, stream>>>(xb, N, pk + 65536, bq2, bk2, bv2, bs2,
                                         q, k, v, s);
    node_attn_k<false><<<gN16, TPB, 0, stream>>>(q, k, v, s, We2, row_ptr, csr_pair,
                                                 outf, N);
}